// Round 17
// baseline (1569.504 us; speedup 1.0000x reference)
//
#include <hip/hip_runtime.h>
#include <hip/hip_fp16.h>

// 2-layer LSTM B=256 T=512 I=32 H=256.  r16 (1198us proven) + W1 fused into L0.
// 16 groups x 16 batches x 8 wgs (256 thr, 4 waves, __launch_bounds__(256,1)):
//   L0W x4 quarters: Whh0+Wih0+Wih1(quarter) register-resident (~340 VGPR);
//     per step: stage h0[t-1] -> recurrence h0[t] -> store -> PRE-ISSUE next
//     stage loads -> xg[t-1]=Wih1_q*h0[t-1]+b1 from same LDS -> store xg.
//   L1 x4 quarters: Whh1 regs, stage xg[t]+h1[t-1], add, elementwise, output.
// Rings (all sc0 sc1 MALL, fp16-LSB lap tags, fire-and-forget):
//   h0: 16 slots x 8KB; readers = L0W only (skew<=1 structural, NO throttle).
//   xg: 4 slots x [4 x 8KB]; L0W q -> L1 q; throttle L1prog >= t-4 (period 8).
//   h1: 2 slots x 8KB; L1 quarters, skew<=1 structural.
// Fallback: r9 kernel (1580us proven) when ws too small.

#define TT 512
#define HH 256
#define GS 294912   // per-group: 128K h0 + 16K h1r + 128K xg + prog

typedef _Float16 f16x8 __attribute__((ext_vector_type(8)));
typedef float    f32x4 __attribute__((ext_vector_type(4)));
typedef unsigned u32x4 __attribute__((ext_vector_type(4)));

__device__ __forceinline__ f16x8 cvt8(const float* p) {
  const float4 a = *(const float4*)p;
  const float4 b = *(const float4*)(p + 4);
  f16x8 r;
  r[0]=(_Float16)a.x; r[1]=(_Float16)a.y; r[2]=(_Float16)a.z; r[3]=(_Float16)a.w;
  r[4]=(_Float16)b.x; r[5]=(_Float16)b.y; r[6]=(_Float16)b.z; r[7]=(_Float16)b.w;
  return r;
}
__device__ __forceinline__ float sigm(float x){ return 1.f/(1.f + __expf(-x)); }
__device__ __forceinline__ float tanh_(float x){ return 1.f - 2.f/(1.f + __expf(2.f*x)); }

// ---- MALL-coherent (L2-bypass) primitives, per-lane 64b addressing ----
__device__ __forceinline__ u32x4 ld16(const void* p) {
  u32x4 r;
  asm volatile("global_load_dwordx4 %0, %1, off sc0 sc1"
               : "=v"(r) : "v"(p) : "memory");
  return r;
}
__device__ __forceinline__ void st2(void* p, unsigned v) {
  asm volatile("global_store_short %0, %1, off sc0 sc1"
               :: "v"(p), "v"(v) : "memory");
}
__device__ __forceinline__ void stp(void* p, unsigned v) {
  asm volatile("global_store_dword %0, %1, off sc0 sc1"
               :: "v"(p), "v"(v) : "memory");
}
__device__ __forceinline__ unsigned ldp(const void* p) {
  unsigned r;
  asm volatile("global_load_dword %0, %1, off sc0 sc1\n\ts_waitcnt vmcnt(0)"
               : "=v"(r) : "v"(p) : "memory");
  return r;
}
__device__ __forceinline__ void wvm0() {
  asm volatile("s_waitcnt vmcnt(0)" ::: "memory");
  __builtin_amdgcn_sched_barrier(0);
}
__device__ __forceinline__ void barrier_lds() {
  __builtin_amdgcn_sched_barrier(0);
  asm volatile("s_waitcnt lgkmcnt(0)" ::: "memory");
  __builtin_amdgcn_s_barrier();
  __builtin_amdgcn_sched_barrier(0);
}

__global__ void init_ws(uint4* p, int n) {
  int i = blockIdx.x * blockDim.x + threadIdx.x;
  if (i >= n) return;
  int rem = i % (GS / 16);
  p[i] = (rem < 17408) ? make_uint4(0x00010001u,0x00010001u,0x00010001u,0x00010001u)
                       : make_uint4(0u,0u,0u,0u);   // prog dwords = 0
}

__global__ __launch_bounds__(256, 1) void lstm_v17(
    const float* __restrict__ M,
    const float* __restrict__ Wih0, const float* __restrict__ Whh0,
    const float* __restrict__ bih0, const float* __restrict__ bhh0,
    const float* __restrict__ Wih1, const float* __restrict__ Whh1,
    const float* __restrict__ bih1, const float* __restrict__ bhh1,
    float* __restrict__ out, char* __restrict__ ws)
{
  __shared__ __align__(16) char ldsA[16384];   // 2-parity staged A-frag buffer
  __shared__ __align__(16) char ldsB[16384];   // L1 only: 2-parity staged xg

  const int tid  = threadIdx.x, lane = tid & 63, wv = tid >> 6;   // 4 waves
  const int bid  = blockIdx.x;
  const int g    = bid >> 3;
  const int idx  = bid & 7;
  const int role = idx >> 2;           // 0:L0W  1:L1
  const int q4   = idx & 3;            // quarter
  const int col16 = lane & 15, ko8 = (lane >> 4) << 3, brow = (lane >> 4) << 2;
  const int unit = q4 * 64 + wv * 16 + col16;    // 0..255

  char* base   = ws + (size_t)g * GS;
  char* stream = base;                 // h0: 16 slots x 8KB, A-frag layout
  char* h1r    = base + 131072;        // h1: 2 slots x 8KB, A-frag layout
  char* xg     = base + 147456;        // xg: 4 slots x [4 quarter x 8KB]
  int*  prog   = (int*)(base + 278528);   // [4..7] = L1 quarter progress

  // A-frag byte position of (batch b, unit u): ubase|(b<<4)  [r10-validated]
  const unsigned ubase = ((unsigned)(unit >> 5) << 10)
                       | ((unsigned)((unit >> 3) & 3) << 8)
                       | ((unsigned)(unit & 7) << 1);

  // ---- register-resident weights ----
  f16x8 W0[4][8], W1q[4][8], WI[4];
  float bias0[4] = {0,0,0,0}, bias1[4] = {0,0,0,0};
  if (role == 0) {
    #pragma unroll
    for (int q = 0; q < 4; ++q) {
      const int row = q * HH + unit;
      #pragma unroll
      for (int kt = 0; kt < 8; ++kt) {
        W0[q][kt]  = cvt8(Whh0 + (size_t)row * HH + kt * 32 + ko8);
        W1q[q][kt] = cvt8(Wih1 + (size_t)row * HH + kt * 32 + ko8);
      }
      WI[q]    = cvt8(Wih0 + (size_t)row * 32 + ko8);
      bias0[q] = bih0[row] + bhh0[row];
      bias1[q] = bih1[row] + bhh1[row];
    }
  } else {
    #pragma unroll
    for (int q = 0; q < 4; ++q) {
      const int row = q * HH + unit;
      #pragma unroll
      for (int kt = 0; kt < 8; ++kt)
        W0[q][kt] = cvt8(Whh1 + (size_t)row * HH + kt * 32 + ko8);
    }
  }

  float cst[4] = {0.f, 0.f, 0.f, 0.f};

  if (role == 0) {
    // ============ L0W quarters: recurrence + fused xg production ============
    const float* mp = M + (size_t)(g * 16 + col16) * TT * 32 + ko8;
    float4 m0 = *(const float4*)mp, m1 = *(const float4*)(mp + 4);
    int lastL = 0;
    u32x4 v0, v1;                      // pre-issued staging registers
    for (int t = 0; t <= TT; ++t) {
      const int par = (t - 1) & 1;
      if (t >= 1) {                    // finish cooperative stage of h0[t-1]
        const char* s = stream + (size_t)((t - 1) & 15) * 8192 + tid * 16;
        const unsigned pat = (((unsigned)(t - 1) >> 4) & 1u) * 0x00010001u;
        wvm0();                        // v0,v1 pre-issued at tail of t-1
        for (;;) {
          const u32x4 d = ((v0 ^ pat) | (v1 ^ pat)) & 0x00010001u;
          if (__all((d[0] | d[1] | d[2] | d[3]) == 0)) break;
          v0 = ld16(s); v1 = ld16(s + 4096);
          wvm0();
        }
        *(u32x4*)(ldsA + par * 8192 + tid * 16)        = v0;
        *(u32x4*)(ldsA + par * 8192 + tid * 16 + 4096) = v1;
      }
      barrier_lds();
      if (t < TT) {
        // ---- recurrence: h0[t] ----
        f32x4 acc[4];
        f16x8 am;
        am[0]=(_Float16)m0.x; am[1]=(_Float16)m0.y; am[2]=(_Float16)m0.z; am[3]=(_Float16)m0.w;
        am[4]=(_Float16)m1.x; am[5]=(_Float16)m1.y; am[6]=(_Float16)m1.z; am[7]=(_Float16)m1.w;
        #pragma unroll
        for (int q = 0; q < 4; ++q) {
          acc[q] = (f32x4){bias0[q], bias0[q], bias0[q], bias0[q]};
          acc[q] = __builtin_amdgcn_mfma_f32_16x16x32_f16(am, WI[q], acc[q], 0, 0, 0);
        }
        if (t >= 1) {
          #pragma unroll
          for (int kt = 0; kt < 8; ++kt) {
            const f16x8 A = *(const f16x8*)(ldsA + par * 8192 + kt * 1024 + lane * 16);
            #pragma unroll
            for (int q = 0; q < 4; ++q)
              acc[q] = __builtin_amdgcn_mfma_f32_16x16x32_f16(A, W0[q][kt], acc[q], 0, 0, 0);
          }
        }
        if (t + 1 < TT) { m0 = *(const float4*)(mp + (t + 1) * 32);
                          m1 = *(const float4*)(mp + (t + 1) * 32 + 4); }
        char* slot = stream + (size_t)(t & 15) * 8192;
        const unsigned wt = ((unsigned)t >> 4) & 1u;
        #pragma unroll
        for (int r = 0; r < 4; ++r) {
          const float iv = sigm(acc[0][r]), fv = sigm(acc[1][r]);
          const float gv = tanh_(acc[2][r]), ov = sigm(acc[3][r]);
          cst[r] = fv * cst[r] + iv * gv;
          const float h = ov * tanh_(cst[r]);
          unsigned short hb = __builtin_bit_cast(unsigned short, (_Float16)h);
          hb = (unsigned short)((hb & 0xFFFEu) | wt);
          st2(slot + ubase + ((unsigned)(brow + r) << 4), (unsigned)hb);
        }
        // ---- pre-issue next staging loads (slot t) -> RTT hidden under xg ----
        const char* sn = stream + (size_t)(t & 15) * 8192 + tid * 16;
        v0 = ld16(sn); v1 = ld16(sn + 4096);
      }
      if (t >= 1) {
        // ---- fused xg[t-1] = Wih1_q * h0[t-1] + b1 (same staged LDS) ----
        f32x4 axg[4];
        #pragma unroll
        for (int q = 0; q < 4; ++q)
          axg[q] = (f32x4){bias1[q], bias1[q], bias1[q], bias1[q]};
        #pragma unroll
        for (int kt = 0; kt < 8; ++kt) {
          const f16x8 A = *(const f16x8*)(ldsA + par * 8192 + kt * 1024 + lane * 16);
          #pragma unroll
          for (int q = 0; q < 4; ++q)
            axg[q] = __builtin_amdgcn_mfma_f32_16x16x32_f16(A, W1q[q][kt], axg[q], 0, 0, 0);
        }
        if (t >= 5) {                  // xg slot overwrite throttle vs L1 q
          while (lastL < t - 4) lastL = (int)ldp(prog + 4 + q4);
        }
        char* xs = xg + (size_t)((t - 1) & 3) * 32768 + q4 * 8192;
        const unsigned wtx = (((unsigned)(t - 1)) >> 2) & 1u;
        #pragma unroll
        for (int q = 0; q < 4; ++q)
          #pragma unroll
          for (int r = 0; r < 4; ++r) {
            unsigned short hb = __builtin_bit_cast(unsigned short, (_Float16)axg[q][r]);
            hb = (unsigned short)((hb & 0xFFFEu) | wtx);
            const unsigned off = (unsigned)(brow + r) * 512
                               + (unsigned)(q * 64 + wv * 16 + col16) * 2;
            st2(xs + off, (unsigned)hb);
          }
      }
    }
  } else {
    // ============ L1 quarters: recurrence + xg add + output ============
    for (int t = 0; t < TT; ++t) {
      const int par = t & 1;
      {                                // stage xg[t] quarter (8KB) + h1[t-1] (8KB)
        const char* sx = xg + (size_t)(t & 3) * 32768 + q4 * 8192 + tid * 16;
        const unsigned patX = (((unsigned)t >> 2) & 1u) * 0x00010001u;
        const char* sh = h1r + (size_t)((t - 1) & 1) * 8192 + tid * 16;
        const unsigned patH = (((unsigned)(t - 1) >> 1) & 1u) * 0x00010001u;
        const bool hasH = (t >= 1);
        u32x4 x0 = ld16(sx), x1 = ld16(sx + 4096), h0v, h1v;
        if (hasH) { h0v = ld16(sh); h1v = ld16(sh + 4096); }
        wvm0();
        for (;;) {
          u32x4 d = ((x0 ^ patX) | (x1 ^ patX)) & 0x00010001u;
          unsigned bad = d[0] | d[1] | d[2] | d[3];
          if (hasH) {
            const u32x4 e = ((h0v ^ patH) | (h1v ^ patH)) & 0x00010001u;
            bad |= e[0] | e[1] | e[2] | e[3];
          }
          if (__all(bad == 0)) break;
          x0 = ld16(sx); x1 = ld16(sx + 4096);
          if (hasH) { h0v = ld16(sh); h1v = ld16(sh + 4096); }
          wvm0();
        }
        *(u32x4*)(ldsB + par * 8192 + tid * 16)        = x0;
        *(u32x4*)(ldsB + par * 8192 + tid * 16 + 4096) = x1;
        if (hasH) {
          *(u32x4*)(ldsA + par * 8192 + tid * 16)        = h0v;
          *(u32x4*)(ldsA + par * 8192 + tid * 16 + 4096) = h1v;
        }
      }
      barrier_lds();
      if (tid == 0) stp(prog + 4 + q4, (unsigned)(t + 1));
      f32x4 acc[4];
      #pragma unroll
      for (int q = 0; q < 4; ++q) acc[q] = (f32x4){0.f, 0.f, 0.f, 0.f};
      if (t >= 1) {
        #pragma unroll
        for (int kt = 0; kt < 8; ++kt) {
          const f16x8 A = *(const f16x8*)(ldsA + par * 8192 + kt * 1024 + lane * 16);
          #pragma unroll
          for (int q = 0; q < 4; ++q)
            acc[q] = __builtin_amdgcn_mfma_f32_16x16x32_f16(A, W0[q][kt], acc[q], 0, 0, 0);
        }
      }
      const char* xl = ldsB + par * 8192;
      #pragma unroll
      for (int q = 0; q < 4; ++q)
        #pragma unroll
        for (int r = 0; r < 4; ++r) {
          const unsigned short xv = *(const unsigned short*)
            (xl + (brow + r) * 512 + (q * 64 + wv * 16 + col16) * 2);
          acc[q][r] += (float)__builtin_bit_cast(_Float16, xv);
        }
      char* d1 = h1r + (size_t)par * 8192;
      const unsigned wt = ((unsigned)t >> 1) & 1u;
      #pragma unroll
      for (int r = 0; r < 4; ++r) {
        const float iv = sigm(acc[0][r]), fv = sigm(acc[1][r]);
        const float gv = tanh_(acc[2][r]), ov = sigm(acc[3][r]);
        cst[r] = fv * cst[r] + iv * gv;
        const float h = ov * tanh_(cst[r]);
        if (t < TT - 1) {
          unsigned short hb = __builtin_bit_cast(unsigned short, (_Float16)h);
          hb = (unsigned short)((hb & 0xFFFEu) | wt);
          st2(d1 + ubase + ((unsigned)(brow + r) << 4), (unsigned)hb);
        } else {
          out[(size_t)(g * 16 + brow + r) * HH + unit] = h;   // final h1, fp32
        }
      }
    }
  }
}

// ================= fallback: round-9 kernel (1580us proven) =================
__global__ void fb_init(uint4* p, int n) {
  int i = blockIdx.x * blockDim.x + threadIdx.x;
  if (i < n) p[i] = make_uint4(0x00010001u,0x00010001u,0x00010001u,0x00010001u);
}
__device__ __forceinline__ unsigned fb_tg(int t){ return ((unsigned)(t + 4) >> 1) & 1u; }

__global__ __launch_bounds__(512) void lstm_v9(
    const float* __restrict__ M,
    const float* __restrict__ Wih0, const float* __restrict__ Whh0,
    const float* __restrict__ bih0, const float* __restrict__ bhh0,
    const float* __restrict__ Wih1, const float* __restrict__ Whh1,
    const float* __restrict__ bih1, const float* __restrict__ bhh1,
    float* __restrict__ out, char* __restrict__ ws)
{
  __shared__ __align__(16) char  ldsA[16384];
  __shared__ __align__(16) f32x4 xch[8][64];
  const int tid  = threadIdx.x, lane = tid & 63, wv = tid >> 6;
  const int g = blockIdx.x & 7, w = blockIdx.x >> 3;
  const int hf = wv & 1, role = wv >> 1;
  const int col16 = lane & 15, ko8 = (lane >> 4) << 3;
  const int unit = w * 16 + col16;
  #define H0R(slot) (ws + (((g << 1) | (slot)) << 14))
  #define H1R(slot) (ws + 262144 + (((g << 1) | (slot)) << 14))
  f16x8 W0[4][8], WI[4];
  float bias[4] = {0.f, 0.f, 0.f, 0.f};
  if (role == 0) {
    #pragma unroll
    for (int q = 0; q < 4; ++q) {
      const int row = q * HH + unit;
      #pragma unroll
      for (int kt = 0; kt < 8; ++kt) W0[q][kt] = cvt8(Whh0 + (size_t)row*HH + kt*32 + ko8);
      WI[q] = cvt8(Wih0 + (size_t)row*32 + ko8); bias[q] = bih0[row] + bhh0[row];
    }
  } else if (role == 1) {
    #pragma unroll
    for (int q = 0; q < 4; ++q) {
      const int row = q * HH + unit;
      #pragma unroll
      for (int kt = 0; kt < 8; ++kt) W0[q][kt] = cvt8(Wih1 + (size_t)row*HH + kt*32 + ko8);
      bias[q] = bih1[row] + bhh1[row];
    }
  } else if (role == 2) {
    #pragma unroll
    for (int q = 0; q < 4; ++q) {
      const int row = q * HH + unit;
      #pragma unroll
      for (int kt = 0; kt < 8; ++kt) W0[q][kt] = cvt8(Whh1 + (size_t)row*HH + kt*32 + ko8);
    }
  }
  const int sl = tid & 63, skt = (tid >> 6) & 7;
  const unsigned moff0 = (unsigned)((sl & 15) * 512 + skt * 64 + (sl >> 4) * 16);
  const unsigned moff1 = moff0 + 16 * 512;
  const unsigned lo    = (unsigned)(skt * 1024 + sl * 16);
  const unsigned hoff = (((unsigned)(hf*16 + col16)) << 9) | ((unsigned)(lane >> 4) << 4);
  unsigned soff[4];
  #pragma unroll
  for (int r = 0; r < 4; ++r)
    soff[r] = (((unsigned)(hf*16 + ((lane>>4)<<2) + r)) << 9) | ((unsigned)unit << 1);
  const float* mp = M + (size_t)(g*32 + hf*16 + col16) * TT * 32 + ko8;
  float4 m0 = {0,0,0,0}, m1 = {0,0,0,0};
  if (role == 0) { m0 = *(const float4*)mp; m1 = *(const float4*)(mp + 4); }
  float cst[4] = {0.f, 0.f, 0.f, 0.f};
  for (int p = 0; p <= TT; ++p) {
    if (p >= 1) {
      const char* s = H0R((p - 1) & 1);
      const unsigned pat = fb_tg(p - 1) * 0x00010001u;
      u32x4 v0 = ld16(s + moff0), v1 = ld16(s + moff1);
      wvm0();
      for (;;) {
        const u32x4 d = ((v0 ^ pat) | (v1 ^ pat)) & 0x00010001u;
        if (__all((d[0] | d[1] | d[2] | d[3]) == 0)) break;
        v0 = ld16(s + moff0); v1 = ld16(s + moff1); wvm0();
      }
      *(u32x4*)(ldsA + lo) = v0; *(u32x4*)(ldsA + 8192 + lo) = v1;
    }
    barrier_lds();
    f32x4 acc[4];
    if (role == 0 && p < TT) {
      f16x8 am;
      am[0]=(_Float16)m0.x; am[1]=(_Float16)m0.y; am[2]=(_Float16)m0.z; am[3]=(_Float16)m0.w;
      am[4]=(_Float16)m1.x; am[5]=(_Float16)m1.y; am[6]=(_Float16)m1.z; am[7]=(_Float16)m1.w;
      #pragma unroll
      for (int q = 0; q < 4; ++q) {
        acc[q] = (f32x4){bias[q], bias[q], bias[q], bias[q]};
        acc[q] = __builtin_amdgcn_mfma_f32_16x16x32_f16(am, WI[q], acc[q], 0, 0, 0);
      }
      if (p >= 1) {
        #pragma unroll
        for (int kt = 0; kt < 8; ++kt) {
          const f16x8 A = *(const f16x8*)(ldsA + hf*8192 + kt*1024 + lane*16);
          #pragma unroll
          for (int q = 0; q < 4; ++q)
            acc[q] = __builtin_amdgcn_mfma_f32_16x16x32_f16(A, W0[q][kt], acc[q], 0, 0, 0);
        }
      }
      char* d = H0R(p & 1);
      const unsigned wt = fb_tg(p);
      #pragma unroll
      for (int r = 0; r < 4; ++r) {
        const float iv = sigm(acc[0][r]), fv = sigm(acc[1][r]);
        const float gv = tanh_(acc[2][r]), ov = sigm(acc[3][r]);
        cst[r] = fv * cst[r] + iv * gv;
        const float h = ov * tanh_(cst[r]);
        unsigned short hb = __builtin_bit_cast(unsigned short, (_Float16)h);
        hb = (unsigned short)((hb & 0xFFFEu) | wt);
        st2(d + soff[r], (unsigned)hb);
      }
      if (p + 1 < TT) { m0 = *(const float4*)(mp + (p+1)*32); m1 = *(const float4*)(mp + (p+1)*32 + 4); }
    } else if (role == 1 && p >= 1) {
      #pragma unroll
      for (int q = 0; q < 4; ++q) acc[q] = (f32x4){bias[q], bias[q], bias[q], bias[q]};
      #pragma unroll
      for (int kt = 0; kt < 8; ++kt) {
        const f16x8 A = *(const f16x8*)(ldsA + hf*8192 + kt*1024 + lane*16);
        #pragma unroll
        for (int q = 0; q < 4; ++q)
          acc[q] = __builtin_amdgcn_mfma_f32_16x16x32_f16(A, W0[q][kt], acc[q], 0, 0, 0);
      }
    } else if (role == 2 && p >= 2) {
      const char* s = H1R(p & 1);
      const unsigned pat = fb_tg(p - 2) * 0x00010001u;
      u32x4 hb[8];
      #pragma unroll
      for (int k = 0; k < 8; ++k) hb[k] = ld16(s + hoff + k*64);
      wvm0();
      for (;;) {
        unsigned bad = 0;
        #pragma unroll
        for (int k = 0; k < 8; ++k) {
          const u32x4 d = (hb[k] ^ pat) & 0x00010001u;
          bad |= d[0] | d[1] | d[2] | d[3];
        }
        if (__all(bad == 0)) break;
        #pragma unroll
        for (int k = 0; k < 8; ++k) hb[k] = ld16(s + hoff + k*64);
        wvm0();
      }
      #pragma unroll
      for (int q = 0; q < 4; ++q) acc[q] = (f32x4){0.f, 0.f, 0.f, 0.f};
      #pragma unroll
      for (int kt = 0; kt < 8; ++kt) {
        const f16x8 A = __builtin_bit_cast(f16x8, hb[kt]);
        #pragma unroll
        for (int q = 0; q < 4; ++q)
          acc[q] = __builtin_amdgcn_mfma_f32_16x16x32_f16(A, W0[q][kt], acc[q], 0, 0, 0);
      }
      #pragma unroll
      for (int q = 0; q < 4; ++q) xch[hf*4 + q][lane] = acc[q];
    }
    barrier_lds();
    if (role == 1 && p >= 1) {
      if (p >= 2) {
        #pragma unroll
        for (int q = 0; q < 4; ++q) acc[q] = acc[q] + xch[hf*4 + q][lane];
      }
      if (p < TT) {
        char* d = H1R((p - 1) & 1);
        const unsigned wt = fb_tg(p - 1);
        #pragma unroll
        for (int r = 0; r < 4; ++r) {
          const float iv = sigm(acc[0][r]), fv = sigm(acc[1][r]);
          const float gv = tanh_(acc[2][r]), ov = sigm(acc[3][r]);
          cst[r] = fv * cst[r] + iv * gv;
          const float h = ov * tanh_(cst[r]);
          unsigned short hb = __builtin_bit_cast(unsigned short, (_Float16)h);
          hb = (unsigned short)((hb & 0xFFFEu) | wt);
          st2(d + soff[r], (unsigned)hb);
        }
      } else {
        #pragma unroll
        for (int r = 0; r < 4; ++r) {
          const float iv = sigm(acc[0][r]), fv = sigm(acc[1][r]);
          const float gv = tanh_(acc[2][r]), ov = sigm(acc[3][r]);
          cst[r] = fv * cst[r] + iv * gv;
          const float h = ov * tanh_(cst[r]);
          const int b = hf*16 + ((lane>>4)<<2) + r;
          out[(size_t)(g*32 + b) * HH + (w*16 + col16)] = h;
        }
      }
    }
  }
  #undef H0R
  #undef H1R
}

extern "C" void kernel_launch(void* const* d_in, const int* in_sizes, int n_in,
                              void* d_out, int out_size, void* d_ws, size_t ws_size,
                              hipStream_t stream) {
  (void)in_sizes; (void)n_in; (void)out_size;
  const float* M    = (const float*)d_in[0];
  const float* Wih0 = (const float*)d_in[1];
  const float* Whh0 = (const float*)d_in[2];
  const float* bih0 = (const float*)d_in[3];
  const float* bhh0 = (const float*)d_in[4];
  const float* Wih1 = (const float*)d_in[5];
  const float* Whh1 = (const float*)d_in[6];
  const float* bih1 = (const float*)d_in[7];
  const float* bhh1 = (const float*)d_in[8];

  if (ws_size >= (size_t)16 * GS) {
    const int n16 = 16 * (GS / 16);
    init_ws<<<(n16 + 255) / 256, 256, 0, stream>>>((uint4*)d_ws, n16);
    lstm_v17<<<128, 256, 0, stream>>>(M, Wih0, Whh0, bih0, bhh0,
                                      Wih1, Whh1, bih1, bhh1,
                                      (float*)d_out, (char*)d_ws);
  } else {
    if (ws_size < 524288) return;
    fb_init<<<128, 256, 0, stream>>>((uint4*)d_ws, 32768);
    lstm_v9<<<128, 512, 0, stream>>>(M, Wih0, Whh0, bih0, bhh0,
                                     Wih1, Whh1, bih1, bhh1,
                                     (float*)d_out, (char*)d_ws);
  }
}